// Round 1
// baseline (261.079 us; speedup 1.0000x reference)
//
#include <hip/hip_runtime.h>
#include <cstdint>
#include <cstddef>

#define B_   256
#define D_   2048
#define U_   2048
#define NTOT 8192    // 4*U
#define BN   32
#define BK   64
#define KC   2048    // K per ksplit (ksplit=2 over K=4096)
#define ITERS (KC / BK)   // 32

typedef _Float16 half8 __attribute__((ext_vector_type(8)));
typedef float floatx16 __attribute__((ext_vector_type(16)));

// ---------------------------------------------------------------------------
// prep: [x|h] fp32 -> f16, chunk-major layout [chunk=k/8][row][8] so the GEMM
// reads each MFMA A-fragment as one lane-contiguous global_load_dwordx4.
// ---------------------------------------------------------------------------
__global__ __launch_bounds__(256) void prep_kernel(
    const float* __restrict__ x, const float* __restrict__ h,
    _Float16* __restrict__ Ahi)
{
    int gid   = blockIdx.x * 256 + threadIdx.x;   // 131072 total
    int chunk = gid >> 8;                         // 0..511
    int row   = gid & 255;                        // 0..255
    int col0  = chunk * 8;
    const float* src = (col0 < D_) ? (x + row * D_ + col0)
                                   : (h + row * U_ + (col0 - D_));
    float4 v0 = *(const float4*)(src);
    float4 v1 = *(const float4*)(src + 4);
    float v[8] = {v0.x, v0.y, v0.z, v0.w, v1.x, v1.y, v1.z, v1.w};
    half8 hi;
#pragma unroll
    for (int i = 0; i < 8; ++i) hi[i] = (_Float16)v[i];
    *(half8*)(Ahi + (chunk * 256 + row) * 8) = hi;
}

// ---------------------------------------------------------------------------
// GEMM v2: A is NOT staged in LDS. A (2 MB f16) is L2-resident; each wave
// loads its MFMA A-fragments directly global->VGPR (dwordx4, L2 hit),
// double-buffered one kin ahead. Only B (weights) goes through LDS:
// reg-staged fp32->f16, [col][k] layout with XOR swizzle so each B-fragment
// is one conflict-free ds_read_b128. LDS = 8 KB total -> 4 blocks/CU.
// B global loads for kk+1 issue before the compute phase (issue-early /
// write-late), so HBM latency hides under the 8 MFMAs per wave-iteration.
// ---------------------------------------------------------------------------
__global__ __launch_bounds__(256, 4) void gemm_kernel(
    const _Float16* __restrict__ Ahi,
    const float* __restrict__ Wz, const float* __restrict__ Wi,
    const float* __restrict__ Wf, const float* __restrict__ Wo,
    const float* __restrict__ Uz, const float* __restrict__ Ui,
    const float* __restrict__ Uf, const float* __restrict__ Uo,
    float* __restrict__ P)
{
    __shared__ __align__(16) _Float16 sB[2][BK * BN];   // 2 x 4 KB

    const int t    = threadIdx.x;
    const int w    = t >> 6;          // wave 0..3
    const int lane = t & 63;
    const int lg   = lane >> 5;
    const int lm   = lane & 31;

    const int nblk = blockIdx.x;      // 0..255
    const int ks   = blockIdx.y;      // 0..1
    const int n0   = nblk * BN;
    const int g    = n0 >> 11;        // gate 0..3
    const int c0   = n0 & (U_ - 1);

    const float* wsel[8] = {Wz, Wi, Wf, Wo, Uz, Ui, Uf, Uo};
    const float* Bm = wsel[ks * 4 + g];        // ks=0 -> W*, ks=1 -> U*
    const int chunk0 = ks * 256;               // A chunk base (chunk = k/8)

    // B staging: thread t covers col = t&31, k rows sk0..sk0+7
    const int scol = t & 31;
    const int sk0  = (t >> 5) * 8;
    const float* bsrc = Bm + (size_t)sk0 * U_ + c0 + scol;
    // swizzled LDS byte offset ([col][k] f16, 16B-granule XOR swizzle)
    const int swb = (scol * 128 + sk0 * 2) ^ ((scol & 7) << 4);

    // A fragment base: frag(kk,kin): chunk = chunk0 + kk*8 + kin*2 + lg,
    // rows w*64+lm (a0) and +32 (a1); 2048 halfs per chunk.
    const _Float16* a0p = Ahi +
        ((size_t)(chunk0 + lg) * 256 + (size_t)(w * 64 + lm)) * 8;

    floatx16 acc[2] = {};

    // ---- prologue: stage B(0) into buf 0
    {
        float v[8];
#pragma unroll
        for (int j = 0; j < 8; ++j) v[j] = bsrc[(size_t)j * U_];
        half8 hv;
#pragma unroll
        for (int j = 0; j < 8; ++j) hv[j] = (_Float16)v[j];
        *(half8*)((char*)(&sB[0][0]) + swb) = hv;
    }
    __syncthreads();

    // preload A fragments for (kk=0, kin=0)
    half8 a0c = *(const half8*)(a0p);
    half8 a1c = *(const half8*)(a0p + 256);   // +32 rows * 8 halfs

    for (int kk = 0; kk < ITERS; ++kk) {
        const int cur = kk & 1;

        // issue B global loads for kk+1 early (consumed after compute)
        float bv[8];
        if (kk + 1 < ITERS) {
            const float* s = bsrc + (size_t)(kk + 1) * BK * U_;
#pragma unroll
            for (int j = 0; j < 8; ++j) bv[j] = s[(size_t)j * U_];
        }

        // read this iteration's 4 B-fragments (swizzled ds_read_b128)
        half8 bf[4];
#pragma unroll
        for (int kin = 0; kin < 4; ++kin) {
            int byte = (lm * 128 + (kin * 16 + lg * 8) * 2) ^ ((lm & 7) << 4);
            bf[kin] = *(const half8*)((const char*)(&sB[cur][0]) + byte);
        }

        // 8 MFMAs with A-fragments prefetched one kin ahead (from L2)
        const _Float16* akk = a0p + (size_t)kk * 8 * 2048;
        const int kknext = (kk + 1 < ITERS) ? (kk + 1) : 0;  // wrap: valid addr
#pragma unroll
        for (int kin = 0; kin < 4; ++kin) {
            const _Float16* np = (kin < 3)
                ? (akk + (size_t)(kin + 1) * 2 * 2048)
                : (a0p + (size_t)kknext * 8 * 2048);
            half8 a0n = *(const half8*)np;
            half8 a1n = *(const half8*)(np + 256);
            acc[0] = __builtin_amdgcn_mfma_f32_32x32x16_f16(a0c, bf[kin], acc[0], 0, 0, 0);
            acc[1] = __builtin_amdgcn_mfma_f32_32x32x16_f16(a1c, bf[kin], acc[1], 0, 0, 0);
            a0c = a0n; a1c = a1n;
        }

        // convert + write B(kk+1) into the other buffer (write-late)
        if (kk + 1 < ITERS) {
            half8 hv;
#pragma unroll
            for (int j = 0; j < 8; ++j) hv[j] = (_Float16)bv[j];
            *(half8*)((char*)(&sB[cur ^ 1][0]) + swb) = hv;
        }
        __syncthreads();
    }

    // C/D layout: col=lane&31, row=(r&3)+8*(r>>2)+4*(lane>>5)
    float* Pks = P + (size_t)ks * ((size_t)B_ * NTOT);
#pragma unroll
    for (int mt = 0; mt < 2; ++mt)
#pragma unroll
        for (int r = 0; r < 16; ++r) {
            int m = w * 64 + mt * 32 + 4 * lg + (r & 3) + 8 * (r >> 2);
            Pks[(size_t)m * NTOT + n0 + lm] = acc[mt][r];
        }
}

// ---------------------------------------------------------------------------
// gates: reduce 2 partials, add bias, sLSTM exponential-gate math,
// out = stack([h_t, c_t, n_t, m_t])
// ---------------------------------------------------------------------------
__global__ __launch_bounds__(256) void gates_kernel(
    const float* __restrict__ P,
    const float* __restrict__ c_prev, const float* __restrict__ n_prev,
    const float* __restrict__ m_prev,
    const float* __restrict__ bz, const float* __restrict__ bi,
    const float* __restrict__ bf, const float* __restrict__ bo,
    float* __restrict__ out)
{
    const size_t PS = (size_t)B_ * NTOT;
    const int OS = B_ * U_;
    int gid = blockIdx.x * 256 + threadIdx.x;   // 131072
    int m = gid >> 9;
    int u = (gid & 511) * 4;

    float pre[4][4];
#pragma unroll
    for (int gi = 0; gi < 4; ++gi) {
        const float* base = P + (size_t)m * NTOT + gi * U_ + u;
        float4 s0 = *(const float4*)(base);
        float4 s1 = *(const float4*)(base + PS);
        pre[gi][0] = s0.x + s1.x;
        pre[gi][1] = s0.y + s1.y;
        pre[gi][2] = s0.z + s1.z;
        pre[gi][3] = s0.w + s1.w;
    }
    float4 bzv = *(const float4*)(bz + u);
    float4 biv = *(const float4*)(bi + u);
    float4 bfv = *(const float4*)(bf + u);
    float4 bov = *(const float4*)(bo + u);
    float bza[4] = {bzv.x, bzv.y, bzv.z, bzv.w};
    float bia[4] = {biv.x, biv.y, biv.z, biv.w};
    float bfa[4] = {bfv.x, bfv.y, bfv.z, bfv.w};
    float boa[4] = {bov.x, bov.y, bov.z, bov.w};

    float4 cp4 = *(const float4*)(c_prev + m * U_ + u);
    float4 np4 = *(const float4*)(n_prev + m * U_ + u);
    float4 mp4 = *(const float4*)(m_prev + m * U_ + u);
    float cpa[4] = {cp4.x, cp4.y, cp4.z, cp4.w};
    float npa[4] = {np4.x, np4.y, np4.z, np4.w};
    float mpa[4] = {mp4.x, mp4.y, mp4.z, mp4.w};

    float hr[4], cr[4], nr[4], mr[4];
#pragma unroll
    for (int e = 0; e < 4; ++e) {
        float zt = pre[0][e] + bza[e];
        float it = pre[1][e] + bia[e];
        float ft = pre[2][e] + bfa[e];
        float ot = pre[3][e] + boa[e];
        float mp = mpa[e];
        float m_t = fmaxf(it + mp, it);
        float i_t = expf(it - m_t);
        float f_t = expf(ft + mp - m_t);
        float o_t = 1.0f / (1.0f + expf(-ot));
        float z_t = tanhf(zt);
        float c_t = f_t * cpa[e] + i_t * z_t;
        float n_t = f_t * npa[e] + i_t;
        float h_t = o_t * (c_t / (n_t + 1e-8f));
        hr[e] = h_t; cr[e] = c_t; nr[e] = n_t; mr[e] = m_t;
    }
    float4 hv = {hr[0], hr[1], hr[2], hr[3]};
    float4 cv = {cr[0], cr[1], cr[2], cr[3]};
    float4 nv = {nr[0], nr[1], nr[2], nr[3]};
    float4 mv = {mr[0], mr[1], mr[2], mr[3]};
    *(float4*)(out + 0 * OS + m * U_ + u) = hv;
    *(float4*)(out + 1 * OS + m * U_ + u) = cv;
    *(float4*)(out + 2 * OS + m * U_ + u) = nv;
    *(float4*)(out + 3 * OS + m * U_ + u) = mv;
}

extern "C" void kernel_launch(void* const* d_in, const int* in_sizes, int n_in,
                              void* d_out, int out_size, void* d_ws, size_t ws_size,
                              hipStream_t stream)
{
    const float* x  = (const float*)d_in[0];
    const float* h  = (const float*)d_in[1];
    const float* cp = (const float*)d_in[2];
    const float* np = (const float*)d_in[3];
    const float* mp = (const float*)d_in[4];
    const float* Wz = (const float*)d_in[5];
    const float* Wi = (const float*)d_in[6];
    const float* Wf = (const float*)d_in[7];
    const float* Wo = (const float*)d_in[8];
    const float* bz = (const float*)d_in[9];
    const float* bi = (const float*)d_in[10];
    const float* bf = (const float*)d_in[11];
    const float* bo = (const float*)d_in[12];
    const float* Uz = (const float*)d_in[13];
    const float* Ui = (const float*)d_in[14];
    const float* Uf = (const float*)d_in[15];
    const float* Uo = (const float*)d_in[16];

    float* P = (float*)d_ws;                         // 2*256*8192 f32 = 16.8 MB
    _Float16* Ahi = (_Float16*)((char*)d_ws + (size_t)2 * B_ * NTOT * sizeof(float));

    prep_kernel<<<512, 256, 0, stream>>>(x, h, Ahi);
    gemm_kernel<<<dim3(256, 2), 256, 0, stream>>>(Ahi,
        Wz, Wi, Wf, Wo, Uz, Ui, Uf, Uo, P);
    gates_kernel<<<512, 256, 0, stream>>>(P, cp, np, mp, bz, bi, bf, bo,
        (float*)d_out);
}

// Round 2
// 245.641 us; speedup vs baseline: 1.0628x; 1.0628x over previous
//
#include <hip/hip_runtime.h>
#include <cstdint>
#include <cstddef>

#define B_   256
#define D_   2048
#define U_   2048
#define NTOT 8192    // 4*U
#define BN   32
#define BK   64
#define KC   2048    // K per ksplit (ksplit=2 over K=4096)
#define ITERS (KC / BK)   // 32

typedef _Float16 half8 __attribute__((ext_vector_type(8)));
typedef float floatx16 __attribute__((ext_vector_type(16)));

// ---------------------------------------------------------------------------
// prep: [x|h] fp32 -> f16, chunk-major layout [chunk=k/8][row][8] so the GEMM
// reads each MFMA A-fragment as one lane-contiguous global_load_dwordx4.
// ---------------------------------------------------------------------------
__global__ __launch_bounds__(256) void prep_kernel(
    const float* __restrict__ x, const float* __restrict__ h,
    _Float16* __restrict__ Ahi)
{
    int gid   = blockIdx.x * 256 + threadIdx.x;   // 131072 total
    int chunk = gid >> 8;                         // 0..511
    int row   = gid & 255;                        // 0..255
    int col0  = chunk * 8;
    const float* src = (col0 < D_) ? (x + row * D_ + col0)
                                   : (h + row * U_ + (col0 - D_));
    float4 v0 = *(const float4*)(src);
    float4 v1 = *(const float4*)(src + 4);
    float v[8] = {v0.x, v0.y, v0.z, v0.w, v1.x, v1.y, v1.z, v1.w};
    half8 hi;
#pragma unroll
    for (int i = 0; i < 8; ++i) hi[i] = (_Float16)v[i];
    *(half8*)(Ahi + (chunk * 256 + row) * 8) = hi;
}

// ---------------------------------------------------------------------------
// GEMM v3: ZERO LDS, ZERO BARRIERS. Each wave is fully independent.
//
// A-fragments: lane-contiguous 16B loads from the chunk-major f16 buffer
// (L2-resident, 2 MB).  B-fragments: direct per-lane fp32 loads — for fixed
// (kin,j) the wave's 64 lanes cover 2 weight rows x 128 B contiguous, fully
// coalesced, zero waste.  Register double-buffer one full K-step (8 A-loads +
// 32 B-loads) issued before the current step's convert+MFMA, so the compiler
// emits a counted s_waitcnt vmcnt(40) and a full K-step of HBM flight stays
// outstanding per wave.  No lockstep: one wave's stall never blocks another.
// ---------------------------------------------------------------------------
__global__ __launch_bounds__(256, 2) void gemm_kernel(
    const _Float16* __restrict__ Ahi,
    const float* __restrict__ Wz, const float* __restrict__ Wi,
    const float* __restrict__ Wf, const float* __restrict__ Wo,
    const float* __restrict__ Uz, const float* __restrict__ Ui,
    const float* __restrict__ Uf, const float* __restrict__ Uo,
    float* __restrict__ P)
{
    const int t    = threadIdx.x;
    const int w    = t >> 6;          // wave 0..3
    const int lane = t & 63;
    const int lg   = lane >> 5;
    const int lm   = lane & 31;

    const int nblk = blockIdx.x;      // 0..255
    const int ks   = blockIdx.y;      // 0..1
    const int n0   = nblk * BN;
    const int g    = n0 >> 11;        // gate 0..3
    const int c0   = n0 & (U_ - 1);

    const float* wsel[8] = {Wz, Wi, Wf, Wo, Uz, Ui, Uf, Uo};
    const float* Bm = wsel[ks * 4 + g];        // ks=0 -> W*, ks=1 -> U*
    const int chunk0 = ks * 256;               // A chunk base (chunk = k/8)

    // A fragment base: frag(kk,kin): chunk = chunk0 + kk*8 + kin*2 + lg,
    // rows w*64+lm (a0) and +32 (a1); 2048 halfs per chunk.
    const _Float16* a0p = Ahi +
        ((size_t)(chunk0 + lg) * 256 + (size_t)(w * 64 + lm)) * 8;

    // B fragment base: element (kk,kin,j) at row kk*64 + kin*16 + lg*8 + j,
    // col c0+lm.  lg*8 rows folded into the base pointer.
    const float* bp = Bm + (size_t)(lg * 8) * U_ + c0 + lm;

    floatx16 acc0 = {}, acc1 = {};

    // register double-buffers (all indices compile-time after full unroll)
    half8 abuf0[2][4], abuf1[2][4];
    float bbuf[2][32];

#define LOAD_STEP(kk, buf)                                                    \
    {                                                                         \
        _Pragma("unroll")                                                     \
        for (int kin = 0; kin < 4; ++kin) {                                   \
            const _Float16* ap = a0p + ((size_t)(kk) * 8 + kin * 2) * 2048;   \
            abuf0[buf][kin] = *(const half8*)(ap);                            \
            abuf1[buf][kin] = *(const half8*)(ap + 256);                      \
        }                                                                     \
        _Pragma("unroll")                                                     \
        for (int kin = 0; kin < 4; ++kin)                                     \
            _Pragma("unroll")                                                 \
            for (int j = 0; j < 8; ++j)                                       \
                bbuf[buf][kin * 8 + j] =                                      \
                    bp[((size_t)(kk) * 64 + kin * 16 + j) * U_];              \
    }

    LOAD_STEP(0, 0);

#pragma unroll
    for (int kk = 0; kk < ITERS; ++kk) {
        const int cur = kk & 1;
        // issue next step's loads FIRST (stay in flight across this step)
        if (kk + 1 < ITERS) LOAD_STEP(kk + 1, cur ^ 1);

        // convert current B fp32 -> f16 fragments (forces wait on step kk only)
        half8 bf[4];
#pragma unroll
        for (int kin = 0; kin < 4; ++kin)
#pragma unroll
            for (int j = 0; j < 8; ++j)
                bf[kin][j] = (_Float16)bbuf[cur][kin * 8 + j];

#pragma unroll
        for (int kin = 0; kin < 4; ++kin) {
            acc0 = __builtin_amdgcn_mfma_f32_32x32x16_f16(abuf0[cur][kin], bf[kin], acc0, 0, 0, 0);
            acc1 = __builtin_amdgcn_mfma_f32_32x32x16_f16(abuf1[cur][kin], bf[kin], acc1, 0, 0, 0);
        }
    }
#undef LOAD_STEP

    // C/D layout: col=lane&31, row=(r&3)+8*(r>>2)+4*(lane>>5)
    float* Pks = P + (size_t)ks * ((size_t)B_ * NTOT);
#pragma unroll
    for (int r = 0; r < 16; ++r) {
        int m = w * 64 + 4 * lg + (r & 3) + 8 * (r >> 2);
        Pks[(size_t)m * NTOT + n0 + lm] = acc0[r];
    }
#pragma unroll
    for (int r = 0; r < 16; ++r) {
        int m = w * 64 + 32 + 4 * lg + (r & 3) + 8 * (r >> 2);
        Pks[(size_t)m * NTOT + n0 + lm] = acc1[r];
    }
}

// ---------------------------------------------------------------------------
// gates: reduce 2 partials, add bias, sLSTM exponential-gate math,
// out = stack([h_t, c_t, n_t, m_t])
// ---------------------------------------------------------------------------
__global__ __launch_bounds__(256) void gates_kernel(
    const float* __restrict__ P,
    const float* __restrict__ c_prev, const float* __restrict__ n_prev,
    const float* __restrict__ m_prev,
    const float* __restrict__ bz, const float* __restrict__ bi,
    const float* __restrict__ bf, const float* __restrict__ bo,
    float* __restrict__ out)
{
    const size_t PS = (size_t)B_ * NTOT;
    const int OS = B_ * U_;
    int gid = blockIdx.x * 256 + threadIdx.x;   // 131072
    int m = gid >> 9;
    int u = (gid & 511) * 4;

    float pre[4][4];
#pragma unroll
    for (int gi = 0; gi < 4; ++gi) {
        const float* base = P + (size_t)m * NTOT + gi * U_ + u;
        float4 s0 = *(const float4*)(base);
        float4 s1 = *(const float4*)(base + PS);
        pre[gi][0] = s0.x + s1.x;
        pre[gi][1] = s0.y + s1.y;
        pre[gi][2] = s0.z + s1.z;
        pre[gi][3] = s0.w + s1.w;
    }
    float4 bzv = *(const float4*)(bz + u);
    float4 biv = *(const float4*)(bi + u);
    float4 bfv = *(const float4*)(bf + u);
    float4 bov = *(const float4*)(bo + u);
    float bza[4] = {bzv.x, bzv.y, bzv.z, bzv.w};
    float bia[4] = {biv.x, biv.y, biv.z, biv.w};
    float bfa[4] = {bfv.x, bfv.y, bfv.z, bfv.w};
    float boa[4] = {bov.x, bov.y, bov.z, bov.w};

    float4 cp4 = *(const float4*)(c_prev + m * U_ + u);
    float4 np4 = *(const float4*)(n_prev + m * U_ + u);
    float4 mp4 = *(const float4*)(m_prev + m * U_ + u);
    float cpa[4] = {cp4.x, cp4.y, cp4.z, cp4.w};
    float npa[4] = {np4.x, np4.y, np4.z, np4.w};
    float mpa[4] = {mp4.x, mp4.y, mp4.z, mp4.w};

    float hr[4], cr[4], nr[4], mr[4];
#pragma unroll
    for (int e = 0; e < 4; ++e) {
        float zt = pre[0][e] + bza[e];
        float it = pre[1][e] + bia[e];
        float ft = pre[2][e] + bfa[e];
        float ot = pre[3][e] + boa[e];
        float mp = mpa[e];
        float m_t = fmaxf(it + mp, it);
        float i_t = expf(it - m_t);
        float f_t = expf(ft + mp - m_t);
        float o_t = 1.0f / (1.0f + expf(-ot));
        float z_t = tanhf(zt);
        float c_t = f_t * cpa[e] + i_t * z_t;
        float n_t = f_t * npa[e] + i_t;
        float h_t = o_t * (c_t / (n_t + 1e-8f));
        hr[e] = h_t; cr[e] = c_t; nr[e] = n_t; mr[e] = m_t;
    }
    float4 hv = {hr[0], hr[1], hr[2], hr[3]};
    float4 cv = {cr[0], cr[1], cr[2], cr[3]};
    float4 nv = {nr[0], nr[1], nr[2], nr[3]};
    float4 mv = {mr[0], mr[1], mr[2], mr[3]};
    *(float4*)(out + 0 * OS + m * U_ + u) = hv;
    *(float4*)(out + 1 * OS + m * U_ + u) = cv;
    *(float4*)(out + 2 * OS + m * U_ + u) = nv;
    *(float4*)(out + 3 * OS + m * U_ + u) = mv;
}

extern "C" void kernel_launch(void* const* d_in, const int* in_sizes, int n_in,
                              void* d_out, int out_size, void* d_ws, size_t ws_size,
                              hipStream_t stream)
{
    const float* x  = (const float*)d_in[0];
    const float* h  = (const float*)d_in[1];
    const float* cp = (const float*)d_in[2];
    const float* np = (const float*)d_in[3];
    const float* mp = (const float*)d_in[4];
    const float* Wz = (const float*)d_in[5];
    const float* Wi = (const float*)d_in[6];
    const float* Wf = (const float*)d_in[7];
    const float* Wo = (const float*)d_in[8];
    const float* bz = (const float*)d_in[9];
    const float* bi = (const float*)d_in[10];
    const float* bf = (const float*)d_in[11];
    const float* bo = (const float*)d_in[12];
    const float* Uz = (const float*)d_in[13];
    const float* Ui = (const float*)d_in[14];
    const float* Uf = (const float*)d_in[15];
    const float* Uo = (const float*)d_in[16];

    float* P = (float*)d_ws;                         // 2*256*8192 f32 = 16.8 MB
    _Float16* Ahi = (_Float16*)((char*)d_ws + (size_t)2 * B_ * NTOT * sizeof(float));

    prep_kernel<<<512, 256, 0, stream>>>(x, h, Ahi);
    gemm_kernel<<<dim3(256, 2), 256, 0, stream>>>(Ahi,
        Wz, Wi, Wf, Wo, Uz, Ui, Uf, Uo, P);
    gates_kernel<<<512, 256, 0, stream>>>(P, cp, np, mp, bz, bi, bf, bo,
        (float*)d_out);
}

// Round 3
// 205.898 us; speedup vs baseline: 1.2680x; 1.1930x over previous
//
#include <hip/hip_runtime.h>
#include <cstdint>
#include <cstddef>

#define B_   256
#define D_   2048
#define U_   2048
#define NTOT 8192    // 4*U
#define BN   64
#define BK   64
#define KC   2048    // K per ksplit (ksplit=2 over K=4096)
#define ITERS (KC / BK)   // 32

typedef _Float16 half8 __attribute__((ext_vector_type(8)));
typedef float floatx16 __attribute__((ext_vector_type(16)));

// ---------------------------------------------------------------------------
// prep: [x|h] fp32 -> f16, chunk-major layout [chunk=k/8][row][8] so the GEMM
// stages A with contiguous global_load_lds and reads fragments as ds_read_b128.
// ---------------------------------------------------------------------------
__global__ __launch_bounds__(256) void prep_kernel(
    const float* __restrict__ x, const float* __restrict__ h,
    _Float16* __restrict__ Ahi)
{
    int gid   = blockIdx.x * 256 + threadIdx.x;   // 131072 total
    int chunk = gid >> 8;                         // 0..511
    int row   = gid & 255;                        // 0..255
    int col0  = chunk * 8;
    const float* src = (col0 < D_) ? (x + row * D_ + col0)
                                   : (h + row * U_ + (col0 - D_));
    float4 v0 = *(const float4*)(src);
    float4 v1 = *(const float4*)(src + 4);
    float v[8] = {v0.x, v0.y, v0.z, v0.w, v1.x, v1.y, v1.z, v1.w};
    half8 hi;
#pragma unroll
    for (int i = 0; i < 8; ++i) hi[i] = (_Float16)v[i];
    *(half8*)(Ahi + (chunk * 256 + row) * 8) = hi;
}

// ---------------------------------------------------------------------------
// GEMM v4: LDS double-buffer + counted vmcnt + raw s_barrier (T3+T4).
// 512 threads (8 waves, wave-tile 64x32), BN=64, grid (128,2) = 1 block/CU.
// Per K-step: issue A(t+1) global_load_lds -> issue B(t+2) global->regs ->
// compute t -> cvt+swizzled-write B(t+1) -> s_waitcnt vmcnt(8) (B(t+2) stays
// in flight ACROSS the barrier) -> s_barrier.  vmcnt never drains to 0 in
// the main loop.  B lives in LDS as f16, read as conflict-free ds_read_b128.
// ---------------------------------------------------------------------------
__global__ __launch_bounds__(512, 2) void gemm_kernel(
    const _Float16* __restrict__ Ahi,
    const float* __restrict__ Wz, const float* __restrict__ Wi,
    const float* __restrict__ Wf, const float* __restrict__ Wo,
    const float* __restrict__ Uz, const float* __restrict__ Ui,
    const float* __restrict__ Uf, const float* __restrict__ Uo,
    float* __restrict__ P)
{
    __shared__ __align__(16) _Float16 sA[2][8 * 256 * 8];   // 2 x 32 KB
    __shared__ __align__(16) _Float16 sB[2][BK * BN];       // 2 x 8 KB

    const int t    = threadIdx.x;
    const int w    = t >> 6;          // wave 0..7
    const int lane = t & 63;
    const int lg   = lane >> 5;
    const int lm   = lane & 31;
    const int wm   = w >> 1;          // 0..3 : M block (64 rows)
    const int wn   = w & 1;           // 0..1 : N half (32 cols)

    const int nblk = blockIdx.x;      // 0..127
    const int ks   = blockIdx.y;      // 0..1
    const int n0   = nblk * BN;
    const int g    = n0 >> 11;        // gate 0..3
    const int c0   = n0 & (U_ - 1);

    const float* wsel[8] = {Wz, Wi, Wf, Wo, Uz, Ui, Uf, Uo};
    const float* Bm = wsel[ks * 4 + g];        // ks=0 -> W*, ks=1 -> U*
    const int chunk0 = ks * 256;               // A chunk base (chunk = k/8)

    // --- A staging: 4 global_load_lds per thread, linear layout.
    //     global halfs: chunk0*2048 + tile*16384 + (w*4+i)*512 + lane*8
    const _Float16* Ag = Ahi + (size_t)chunk0 * 2048
                             + (size_t)(w * 4) * 512 + (size_t)lane * 8;

    // --- B staging: thread covers col=lane, k rows w*8..w*8+7 (8 coalesced
    //     fp32 loads), converts, writes one swizzled ds_write_b128.
    const float* Bg = Bm + (size_t)(w * 8) * U_ + c0 + lane;
    const int swb = (lane * 128 + w * 16) ^ ((lane & 7) << 4);

    // --- compute-phase A fragment byte offset (per kin add 8192, a1 +512)
    const int aoff = lg * 4096 + (wm * 64 + lm) * 16;

    floatx16 acc0 = {}, acc1 = {};
    float rb0[8], rb1[8];

#define ISSUE_A(tt, buf)                                                      \
    {                                                                         \
        _Pragma("unroll")                                                     \
        for (int i = 0; i < 4; ++i)                                           \
            __builtin_amdgcn_global_load_lds(                                 \
                (const __attribute__((address_space(1))) void*)(              \
                    Ag + (size_t)(tt) * 16384 + i * 512),                     \
                (__attribute__((address_space(3))) void*)(                    \
                    (char*)&sA[buf][0] + (w * 4 + i) * 1024 + lane * 16),     \
                16, 0, 0);                                                    \
    }

#define ISSUE_B(tt, rb)                                                       \
    {                                                                         \
        _Pragma("unroll")                                                     \
        for (int j = 0; j < 8; ++j)                                           \
            rb[j] = Bg[((size_t)(tt) * 64 + j) * U_];                         \
    }

#define WRITE_B(rb, buf)                                                      \
    {                                                                         \
        half8 hv;                                                             \
        _Pragma("unroll")                                                     \
        for (int j = 0; j < 8; ++j) hv[j] = (_Float16)rb[j];                  \
        *(half8*)((char*)&sB[buf][0] + swb) = hv;                             \
    }

#define COMPUTE(cur)                                                          \
    {                                                                         \
        const char* bA = (const char*)&sA[cur][0];                            \
        const char* bB = (const char*)&sB[cur][0];                            \
        half8 af0[4], af1[4], bfr[4];                                         \
        _Pragma("unroll")                                                     \
        for (int kin = 0; kin < 4; ++kin) {                                   \
            af0[kin] = *(const half8*)(bA + aoff + kin * 8192);               \
            af1[kin] = *(const half8*)(bA + aoff + kin * 8192 + 512);         \
            bfr[kin] = *(const half8*)(bB +                                   \
                (((wn * 32 + lm) * 128 + kin * 32 + lg * 16)                  \
                 ^ ((lm & 7) << 4)));                                         \
        }                                                                     \
        __builtin_amdgcn_s_setprio(1);                                        \
        _Pragma("unroll")                                                     \
        for (int kin = 0; kin < 4; ++kin) {                                   \
            acc0 = __builtin_amdgcn_mfma_f32_32x32x16_f16(af0[kin], bfr[kin], acc0, 0, 0, 0); \
            acc1 = __builtin_amdgcn_mfma_f32_32x32x16_f16(af1[kin], bfr[kin], acc1, 0, 0, 0); \
        }                                                                     \
        __builtin_amdgcn_s_setprio(0);                                        \
    }

    // ---- prologue: A(0)->buf0; B(0)->rb1->LDS buf0; B(1)->rb0 stays in flight
    ISSUE_A(0, 0);
    ISSUE_B(0, rb1);
    ISSUE_B(1, rb0);
    WRITE_B(rb1, 0);   // compiler inserts counted vmcnt for rb1 here
    asm volatile("s_waitcnt vmcnt(8) lgkmcnt(0)" ::: "memory");
    __builtin_amdgcn_s_barrier();

    // ---- main loop: t = 0..ITERS-3, manually 2x-unrolled (static reg idx)
    for (int tt = 0; tt < ITERS - 2; tt += 2) {
        // t = tt (even): compute buf0
        ISSUE_A(tt + 1, 1);
        ISSUE_B(tt + 2, rb1);
        COMPUTE(0);
        WRITE_B(rb0, 1);   // B(tt+1); auto-wait leaves A(tt+1)+B(tt+2)
        asm volatile("s_waitcnt vmcnt(8) lgkmcnt(0)" ::: "memory");
        __builtin_amdgcn_s_barrier();

        // t = tt+1 (odd): compute buf1
        ISSUE_A(tt + 2, 0);
        ISSUE_B(tt + 3, rb0);
        COMPUTE(1);
        WRITE_B(rb1, 0);   // B(tt+2)
        asm volatile("s_waitcnt vmcnt(8) lgkmcnt(0)" ::: "memory");
        __builtin_amdgcn_s_barrier();
    }

    // ---- epilogue: t = ITERS-2 (even, buf0), no B(ITERS) exists
    ISSUE_A(ITERS - 1, 1);
    COMPUTE(0);
    WRITE_B(rb0, 1);       // B(ITERS-1)
    asm volatile("s_waitcnt vmcnt(0) lgkmcnt(0)" ::: "memory");
    __builtin_amdgcn_s_barrier();
    // t = ITERS-1 (odd, buf1)
    COMPUTE(1);

#undef ISSUE_A
#undef ISSUE_B
#undef WRITE_B
#undef COMPUTE

    // C/D layout: col=lane&31, row=(r&3)+8*(r>>2)+4*(lane>>5)
    float* Pks = P + (size_t)ks * ((size_t)B_ * NTOT);
    const int ncol = n0 + wn * 32 + lm;
#pragma unroll
    for (int r = 0; r < 16; ++r) {
        int m = wm * 64 + 4 * lg + (r & 3) + 8 * (r >> 2);
        Pks[(size_t)m * NTOT + ncol] = acc0[r];
    }
#pragma unroll
    for (int r = 0; r < 16; ++r) {
        int m = wm * 64 + 32 + 4 * lg + (r & 3) + 8 * (r >> 2);
        Pks[(size_t)m * NTOT + ncol] = acc1[r];
    }
}

// ---------------------------------------------------------------------------
// gates: reduce 2 partials, add bias, sLSTM exponential-gate math,
// out = stack([h_t, c_t, n_t, m_t])
// ---------------------------------------------------------------------------
__global__ __launch_bounds__(256) void gates_kernel(
    const float* __restrict__ P,
    const float* __restrict__ c_prev, const float* __restrict__ n_prev,
    const float* __restrict__ m_prev,
    const float* __restrict__ bz, const float* __restrict__ bi,
    const float* __restrict__ bf, const float* __restrict__ bo,
    float* __restrict__ out)
{
    const size_t PS = (size_t)B_ * NTOT;
    const int OS = B_ * U_;
    int gid = blockIdx.x * 256 + threadIdx.x;   // 131072
    int m = gid >> 9;
    int u = (gid & 511) * 4;

    float pre[4][4];
#pragma unroll
    for (int gi = 0; gi < 4; ++gi) {
        const float* base = P + (size_t)m * NTOT + gi * U_ + u;
        float4 s0 = *(const float4*)(base);
        float4 s1 = *(const float4*)(base + PS);
        pre[gi][0] = s0.x + s1.x;
        pre[gi][1] = s0.y + s1.y;
        pre[gi][2] = s0.z + s1.z;
        pre[gi][3] = s0.w + s1.w;
    }
    float4 bzv = *(const float4*)(bz + u);
    float4 biv = *(const float4*)(bi + u);
    float4 bfv = *(const float4*)(bf + u);
    float4 bov = *(const float4*)(bo + u);
    float bza[4] = {bzv.x, bzv.y, bzv.z, bzv.w};
    float bia[4] = {biv.x, biv.y, biv.z, biv.w};
    float bfa[4] = {bfv.x, bfv.y, bfv.z, bfv.w};
    float boa[4] = {bov.x, bov.y, bov.z, bov.w};

    float4 cp4 = *(const float4*)(c_prev + m * U_ + u);
    float4 np4 = *(const float4*)(n_prev + m * U_ + u);
    float4 mp4 = *(const float4*)(m_prev + m * U_ + u);
    float cpa[4] = {cp4.x, cp4.y, cp4.z, cp4.w};
    float npa[4] = {np4.x, np4.y, np4.z, np4.w};
    float mpa[4] = {mp4.x, mp4.y, mp4.z, mp4.w};

    float hr[4], cr[4], nr[4], mr[4];
#pragma unroll
    for (int e = 0; e < 4; ++e) {
        float zt = pre[0][e] + bza[e];
        float it = pre[1][e] + bia[e];
        float ft = pre[2][e] + bfa[e];
        float ot = pre[3][e] + boa[e];
        float mp = mpa[e];
        float m_t = fmaxf(it + mp, it);
        float i_t = expf(it - m_t);
        float f_t = expf(ft + mp - m_t);
        float o_t = 1.0f / (1.0f + expf(-ot));
        float z_t = tanhf(zt);
        float c_t = f_t * cpa[e] + i_t * z_t;
        float n_t = f_t * npa[e] + i_t;
        float h_t = o_t * (c_t / (n_t + 1e-8f));
        hr[e] = h_t; cr[e] = c_t; nr[e] = n_t; mr[e] = m_t;
    }
    float4 hv = {hr[0], hr[1], hr[2], hr[3]};
    float4 cv = {cr[0], cr[1], cr[2], cr[3]};
    float4 nv = {nr[0], nr[1], nr[2], nr[3]};
    float4 mv = {mr[0], mr[1], mr[2], mr[3]};
    *(float4*)(out + 0 * OS + m * U_ + u) = hv;
    *(float4*)(out + 1 * OS + m * U_ + u) = cv;
    *(float4*)(out + 2 * OS + m * U_ + u) = nv;
    *(float4*)(out + 3 * OS + m * U_ + u) = mv;
}

extern "C" void kernel_launch(void* const* d_in, const int* in_sizes, int n_in,
                              void* d_out, int out_size, void* d_ws, size_t ws_size,
                              hipStream_t stream)
{
    const float* x  = (const float*)d_in[0];
    const float* h  = (const float*)d_in[1];
    const float* cp = (const float*)d_in[2];
    const float* np = (const float*)d_in[3];
    const float* mp = (const float*)d_in[4];
    const float* Wz = (const float*)d_in[5];
    const float* Wi = (const float*)d_in[6];
    const float* Wf = (const float*)d_in[7];
    const float* Wo = (const float*)d_in[8];
    const float* bz = (const float*)d_in[9];
    const float* bi = (const float*)d_in[10];
    const float* bf = (const float*)d_in[11];
    const float* bo = (const float*)d_in[12];
    const float* Uz = (const float*)d_in[13];
    const float* Ui = (const float*)d_in[14];
    const float* Uf = (const float*)d_in[15];
    const float* Uo = (const float*)d_in[16];

    float* P = (float*)d_ws;                         // 2*256*8192 f32 = 16.8 MB
    _Float16* Ahi = (_Float16*)((char*)d_ws + (size_t)2 * B_ * NTOT * sizeof(float));

    prep_kernel<<<512, 256, 0, stream>>>(x, h, Ahi);
    gemm_kernel<<<dim3(128, 2), 512, 0, stream>>>(Ahi,
        Wz, Wi, Wf, Wo, Uz, Ui, Uf, Uo, P);
    gates_kernel<<<512, 256, 0, stream>>>(P, cp, np, mp, bz, bi, bf, bo,
        (float*)d_out);
}